// Round 1
// 135.162 us; speedup vs baseline: 1.0087x; 1.0087x over previous
//
#include <hip/hip_runtime.h>

// PointCrop2D: out[b,i,j,c] = in-bounds ? images[b, y-112+i, x-112+j, c] : -2.0f
// B=32, H=W=512, C=3, CROP=224, fill = (0-0.45)/0.225 = -2.0
//
// Mapping: grid = (147, 32), block = 256. blockIdx.y = batch  -> points fetch,
// clamps and column base are wave-uniform (SALU/s_load). Each thread writes one
// aligned float4 of the output (147*256*4 = 150528 floats = one image exactly).
//
// Column bounds trick: output float p of a row maps to source float
// sf = (x-112)*3 + p + k.  Valid col (0 <= cc <= 510) <=> 0 <= sf <= 1532,
// so no /3 or per-element c/j bookkeeping is needed; one unsigned compare does
// both bounds. Fully-interior float4s (almost all lanes) take a 4-consecutive-
// load fast path off a single base address.

#define B_N   32
#define H_N   512
#define W_N   512
#define C_N   3
#define CROP  224
#define DIA   112
#define FILLV (-2.0f)

__global__ __launch_bounds__(256)
void PointCrop2D_27943057227941_kernel(const float* __restrict__ points,
                                       const float* __restrict__ images,
                                       float* __restrict__ out)
{
    const int ROWF = CROP * C_N;            // 672 floats per output row
    const int IMGF = CROP * ROWF;           // 150528 floats per output image

    const int b = blockIdx.y;               // uniform per block -> scalar path

    // points layout (B,3,3): x = points[b,0,0] -> b*9+0 ; y = points[b,1,0] -> b*9+3
    int xp = (int)points[b * 9 + 0];        // trunc == floor (values >= 0)
    int yp = (int)points[b * 9 + 3];
    int x  = min(max(xp, 1), W_N - 2);
    int y  = min(max(yp, 1), H_N - 2);
    int colbase3 = (x - DIA) * 3;           // uniform source-float column offset
    int rowbase  = y - DIA;                 // uniform first source row

    int t     = blockIdx.x * blockDim.x + threadIdx.x;  // [0, 37632), exact
    int pflat = t << 2;                     // float index within this image
    int i     = (int)((unsigned)pflat / (unsigned)ROWF); // single magic-mul div
    int p     = pflat - i * ROWF;           // [0,672), multiple of 4

    int  r     = rowbase + i;               // source image row
    bool rowok = (unsigned)r <= (unsigned)(H_N - 2);    // row 511 is fill
    int  ra    = min(max(r, 0), H_N - 1);   // clamped for safe addressing

    const float* rowptr = images + ((size_t)b * H_N + (size_t)ra) * (W_N * C_N);

    int S = colbase3 + p;                   // source float index of element 0

    float4 v;
    float* vp = reinterpret_cast<float*>(&v);

    if (rowok && (unsigned)S <= 1529u) {    // S+3 <= 1532: all 4 in-bounds
        vp[0] = rowptr[S + 0];
        vp[1] = rowptr[S + 1];
        vp[2] = rowptr[S + 2];
        vp[3] = rowptr[S + 3];
    } else {                                // boundary waves only (~2 per row)
#pragma unroll
        for (int k = 0; k < 4; ++k) {
            int  sf = S + k;
            bool ok = rowok && ((unsigned)sf <= 1532u); // col in [0,510]
            int  sfa = min(max(sf, 0), W_N * C_N - 1);  // safe address
            vp[k] = ok ? rowptr[sfa] : FILLV;
        }
    }

    size_t og = ((size_t)b * IMGF + (size_t)pflat) >> 2;
    reinterpret_cast<float4*>(out)[og] = v;
}

extern "C" void kernel_launch(void* const* d_in, const int* in_sizes, int n_in,
                              void* d_out, int out_size, void* d_ws, size_t ws_size,
                              hipStream_t stream) {
    const float* points = (const float*)d_in[0];
    const float* images = (const float*)d_in[1];
    float* out = (float*)d_out;

    // 147 blocks * 256 threads * 4 floats = 150528 floats = one image, exact
    dim3 grid(147, B_N);
    PointCrop2D_27943057227941_kernel<<<grid, dim3(256), 0, stream>>>(points, images, out);
}

// Round 3
// 131.629 us; speedup vs baseline: 1.0358x; 1.0268x over previous
//
#include <hip/hip_runtime.h>

// PointCrop2D: out[b,i,j,c] = in-bounds ? images[b, y-112+i, x-112+j, c] : -2.0f
// B=32, H=W=512, C=3, CROP=224, fill = (0-0.45)/0.225 = -2.0
//
// grid = (147, 32), block = 256; blockIdx.y = batch -> points fetch, clamps,
// column base, and the realignment shift sh are all wave-uniform.
//
// Source-float coords: output float p of a row reads source float
// S = (x-112)*3 + p; valid col (0..510) <=> 0 <= S <= 1532.
// Since p % 4 == 0, A = S & ~3 = S - sh with sh = colbase3 & 3 uniform.
// Fast path: 1-2 16B-ALIGNED nontemporal float4 loads + uniform register
// realign (vs 4 stride-16B scalar dwords before: 4x fewer line-requests).
// All traffic is single-use (caches are poisoned by the harness fill each
// iteration) -> nontemporal loads and stores throughout.
//
// NOTE: __builtin_nontemporal_* requires native clang vector types, not
// HIP_vector_type<float,4> -> use ext_vector_type(4).

#define B_N   32
#define H_N   512
#define W_N   512
#define C_N   3
#define CROP  224
#define DIA   112
#define FILLV (-2.0f)

typedef float f32x4 __attribute__((ext_vector_type(4)));

__global__ __launch_bounds__(256)
void PointCrop2D_27943057227941_kernel(const float* __restrict__ points,
                                       const float* __restrict__ images,
                                       float* __restrict__ out)
{
    const int ROWF = CROP * C_N;            // 672 floats per output row
    const int IMGF = CROP * ROWF;           // 150528 floats per output image

    const int b = blockIdx.y;               // uniform -> scalar path

    // points layout (B,3,3): x = points[b,0,0] -> b*9+0 ; y = points[b,1,0] -> b*9+3
    int xp = (int)points[b * 9 + 0];        // trunc == floor (values >= 0)
    int yp = (int)points[b * 9 + 3];
    int x  = min(max(xp, 1), W_N - 2);
    int y  = min(max(yp, 1), H_N - 2);
    int colbase3 = (x - DIA) * 3;           // uniform source-float column offset
    int rowbase  = y - DIA;                 // uniform first source row
    int sh       = colbase3 & 3;            // uniform realignment shift

    int t     = blockIdx.x * blockDim.x + threadIdx.x;  // [0, 37632), exact
    int pflat = t << 2;                     // float index within this image
    int i     = (int)((unsigned)pflat / (unsigned)ROWF); // single magic-mul div
    int p     = pflat - i * ROWF;           // [0,672), multiple of 4

    int  r     = rowbase + i;               // source image row
    bool rowok = (unsigned)r <= (unsigned)(H_N - 2);    // row 511 is fill
    int  ra    = min(max(r, 0), H_N - 1);   // clamped for safe addressing

    const float* rowptr = images + ((size_t)b * H_N + (size_t)ra) * (W_N * C_N);

    int S = colbase3 + p;                   // source float index of element 0

    f32x4 v;

    if (rowok && (unsigned)S <= 1529u) {    // S+3 <= 1532: all 4 in-bounds
        int A = S - sh;                     // = S & ~3: 16B-aligned float4 index
        const f32x4* ap = reinterpret_cast<const f32x4*>(rowptr + A);
        f32x4 lo = __builtin_nontemporal_load(ap);
        if (sh == 0) {                      // uniform branch
            v = lo;
        } else {
            // hi spans A+4..A+7 <= S-1+7 <= 1535 : still inside this row
            f32x4 hi = __builtin_nontemporal_load(ap + 1);
            if (sh == 1)      v = (f32x4){lo.y, lo.z, lo.w, hi.x};
            else if (sh == 2) v = (f32x4){lo.z, lo.w, hi.x, hi.y};
            else              v = (f32x4){lo.w, hi.x, hi.y, hi.z};
        }
    } else {                                // boundary / fill lanes only
#pragma unroll
        for (int k = 0; k < 4; ++k) {
            int  sf = S + k;
            bool ok = rowok && ((unsigned)sf <= 1532u); // col in [0,510]
            int  sfa = min(max(sf, 0), W_N * C_N - 1);  // safe address
            v[k] = ok ? rowptr[sfa] : FILLV;
        }
    }

    size_t og = ((size_t)b * IMGF + (size_t)pflat) >> 2;
    __builtin_nontemporal_store(v, reinterpret_cast<f32x4*>(out) + og);
}

extern "C" void kernel_launch(void* const* d_in, const int* in_sizes, int n_in,
                              void* d_out, int out_size, void* d_ws, size_t ws_size,
                              hipStream_t stream) {
    const float* points = (const float*)d_in[0];
    const float* images = (const float*)d_in[1];
    float* out = (float*)d_out;

    // 147 blocks * 256 threads * 4 floats = 150528 floats = one image, exact
    dim3 grid(147, B_N);
    PointCrop2D_27943057227941_kernel<<<grid, dim3(256), 0, stream>>>(points, images, out);
}